// Round 13
// baseline (190.772 us; speedup 1.0000x reference)
//
#include <hip/hip_runtime.h>
#include <hip/hip_bf16.h>
#include <cstdint>

// GAT fused layer: B=4, N=2048, F=128, H=8, HD=16, all fp32 I/O.
// Identity: exp(leaky(si+sj)) = max(exp(si)exp(sj), exp(.2si)exp(.2sj))
// prep: blocks [0,2048) tpack (adj -> transposed u64 mask words, HBM stream
//   first), [2048,3072) proj, block 3072 WoT.  (r11/r12-proven)
// gat v13: 16-wave blocks (8 heads x 2 j-halves) -> 512 blocks x 1024 thr =
//   32 waves/CU (100% occupancy; r12 was grid-capped at 50%). Inside each
//   wave: r12's chunk pipeline (128-j chunks, V direct global->VGPR one
//   chunk ahead, barrier-paced; Ej/Ej5 LDS double-buffered; wave-uniform
//   mask s_loads + inverse_ballot). __launch_bounds__(1024,8) pins VGPR<=64
//   (r12 measured 48). jh pair-combine via LDS (r8-proven), fused
//   out-proj + ELU.

typedef float f32x2 __attribute__((ext_vector_type(2)));
typedef float f32x4 __attribute__((ext_vector_type(4)));
typedef __bf16 bf16x8 __attribute__((ext_vector_type(8)));
typedef unsigned long long u64;

__device__ __forceinline__ float lsel(float v, u64 m, u64 lanebit) {
#if __has_builtin(__builtin_amdgcn_inverse_ballot_w64)
    (void)lanebit;
    return __builtin_amdgcn_inverse_ballot_w64(m) ? v : 0.0f;
#else
    return (m & lanebit) ? v : 0.0f;
#endif
}

__global__ __launch_bounds__(256)
void prep_kernel(const float* __restrict__ x, const float* __restrict__ W,
                 const float* __restrict__ a, const float* __restrict__ Wo,
                 const int* __restrict__ adj,
                 unsigned short* __restrict__ wxT,
                 float2* __restrict__ EI,
                 float* __restrict__ EjT, float* __restrict__ Ej5T,
                 float* __restrict__ WoT,
                 u64* __restrict__ tmask)
{
    const int t = threadIdx.x;

    if (blockIdx.x < 2048) {
        // ---- tpack: adj -> transposed mask words (r11-proven)
        __shared__ int al[16][257];
        const int blk2 = blockIdx.x;
        const int b = blk2 >> 9;
        const int tile = (blk2 >> 2) & 127;
        const int jq = blk2 & 3;
        const int rowbase = b * 2048 + tile * 16;
        const int w = t >> 6, lane = t & 63;
        const int r = lane & 15, jg = lane >> 4;
        const int srow = t >> 4, scol = (t & 15) * 16;

        #pragma unroll
        for (int cc = 0; cc < 2; ++cc) {
            const int jc = jq * 512 + cc * 256;
            const int* gsrc = adj + (size_t)(rowbase + srow) * 2048 + jc + scol;
            #pragma unroll
            for (int q = 0; q < 4; ++q) {
                const int4 v = *reinterpret_cast<const int4*>(&gsrc[q * 4]);
                al[srow][scol + q * 4 + 0] = v.x;
                al[srow][scol + q * 4 + 1] = v.y;
                al[srow][scol + q * 4 + 2] = v.z;
                al[srow][scol + q * 4 + 3] = v.w;
            }
            __syncthreads();
            u64 myw = 0;
            #pragma unroll
            for (int kk = 0; kk < 2; ++kk) {
                const int c0 = w * 64 + kk * 32 + jg * 8;
                const int4 a0 = *reinterpret_cast<const int4*>(&al[r][c0]);
                const int4 a1 = *reinterpret_cast<const int4*>(&al[r][c0 + 4]);
                const int av[8] = {a0.x, a0.y, a0.z, a0.w, a1.x, a1.y, a1.z, a1.w};
                #pragma unroll
                for (int e = 0; e < 8; ++e) {
                    const u64 bal = __ballot(av[e] != 0);
                    const int widx = kk * 8 + e;
                    if (lane == widx) myw = bal;
                }
            }
            __syncthreads();
            const int jtw = jq * 8 + cc * 4 + w;
            if (lane < 16)
                tmask[((size_t)(b * 128 + tile) * 32 + jtw) * 16 + lane] = myw;
        }
        return;
    }

    // ---- proj: blocks [2048,3072), WoT block 3072 (t<128 active)
    const int blk = blockIdx.x - 2048;
    if (blk == 1024) {
        if (t < 128)
            for (int k = 0; k < 128; ++k)
                WoT[k * 128 + t] = Wo[t * 128 + k];
        return;
    }
    __shared__ float xl[8 * 128];
    __shared__ float xw[8 * 128];
    const int row0 = blk * 8;
    if (t < 128) {
        #pragma unroll
        for (int r = 0; r < 8; ++r)
            xl[r * 128 + t] = x[(size_t)(row0 + r) * 128 + t];
    }
    __syncthreads();

    if (t < 128) {
        float acc[8] = {0.f, 0.f, 0.f, 0.f, 0.f, 0.f, 0.f, 0.f};
        for (int k = 0; k < 128; k += 4) {
            const float w0 = W[(k + 0) * 128 + t];
            const float w1 = W[(k + 1) * 128 + t];
            const float w2 = W[(k + 2) * 128 + t];
            const float w3 = W[(k + 3) * 128 + t];
            #pragma unroll
            for (int r = 0; r < 8; ++r) {
                const float4 xv = *reinterpret_cast<const float4*>(&xl[r * 128 + k]);
                acc[r] += xv.x * w0 + xv.y * w1 + xv.z * w2 + xv.w * w3;
            }
        }
        #pragma unroll
        for (int r = 0; r < 8; ++r) xw[r * 128 + t] = acc[r];
    }
    __syncthreads();

    if (t < 128) {
        const int b = row0 >> 11, n0 = row0 & 2047;
        bf16x8 st;
        #pragma unroll
        for (int r = 0; r < 8; ++r) st[r] = (__bf16)xw[r * 128 + t];
        *reinterpret_cast<bf16x8*>(&wxT[((size_t)(b * 128 + t)) * 2048 + n0]) = st;

        const int r = t >> 4, h = (t >> 1) & 7, s = t & 1;
        float dot = 0.f;
        #pragma unroll
        for (int d = 0; d < 16; ++d)
            dot += xw[r * 128 + h * 16 + d] * a[h * 32 + s * 16 + d];
        const float ef  = __expf(dot);
        const float ef5 = __expf(0.2f * dot);
        const int idx = (b * 8 + h) * 2048 + n0 + r;
        if (s) { EjT[idx] = ef; Ej5T[idx] = ef5; }
        else   { float2 ev; ev.x = ef; ev.y = ef5; EI[idx] = ev; }
    }
}

__global__ __launch_bounds__(1024, 8)
void gat_kernel(const u64* __restrict__ tmask,
                const unsigned short* __restrict__ wxT,
                const float2* __restrict__ EI,
                const float* __restrict__ EjT, const float* __restrict__ Ej5T,
                const float* __restrict__ WoT, const float* __restrict__ bo,
                float* __restrict__ out)
{
    const int tid = threadIdx.x;
    const int w = tid >> 6;              // wave 0..15
    const int h = w & 7;                 // head
    const int jh = w >> 3;               // j-half
    const int lane = tid & 63;
    const int r = lane & 15;             // A-frag row / B-frag col (feature)
    const int jg = lane >> 4;
    const int jaof = jg * 8;
    const u64 lanebit = 1ull << lane;
    // XCD-aware bijective swizzle (512 % 8 == 0)
    const int bid = (blockIdx.x & 7) * 64 + (blockIdx.x >> 3);
    const int b = bid >> 7;
    const int tile = bid & 127;
    const int ibase = tile << 4;

    __shared__ __align__(16) float EjL[2][2][8][128];   // [jh][buf][head][j]
    __shared__ __align__(16) float Ej5L[2][2][8][128];
    __shared__ float hacc[16][128];
    __shared__ float hsum[8][16];

    const int eb = (b * 8 + h) * 2048;
    const int jbase = jh * 1024;
    const float2 q0 = EI[eb + ibase + r];
    f32x2 EiE, Ei5E;
    EiE[0] = q0.x; EiE[1] = q0.x; Ei5E[0] = q0.y; Ei5E[1] = q0.y;
    const u64* tmrow = tmask + (size_t)(b * 128 + tile) * 512;

    // V: per-wave-private row of wxT (feature r of head h), jh half
    const unsigned short* vrow = wxT + ((size_t)(b * 128 + h * 16 + r)) * 2048;
    const int jj = lane;
    const float* EjG  = EjT  + eb;
    const float* Ej5G = Ej5T + eb;

    f32x4 acc  = {0.f, 0.f, 0.f, 0.f};
    f32x4 accS = {0.f, 0.f, 0.f, 0.f};
    bf16x8 ones;
    #pragma unroll
    for (int e2 = 0; e2 < 8; ++e2) ones[e2] = (__bf16)1.0f;

    bf16x8 vC0, vC1, vC2, vC3, vN0, vN1, vN2, vN3;
    // ---- prologue: V chunk 0 -> regs, Ej chunk 0 -> LDS buf 0
    vC0 = *reinterpret_cast<const bf16x8*>(&vrow[jbase + jaof]);
    vC1 = *reinterpret_cast<const bf16x8*>(&vrow[jbase + 32 + jaof]);
    vC2 = *reinterpret_cast<const bf16x8*>(&vrow[jbase + 64 + jaof]);
    vC3 = *reinterpret_cast<const bf16x8*>(&vrow[jbase + 96 + jaof]);
    {
        const float2 s0 = *reinterpret_cast<const float2*>(&EjG[jbase + jj * 2]);
        const float2 s1 = *reinterpret_cast<const float2*>(&Ej5G[jbase + jj * 2]);
        *reinterpret_cast<float2*>(&EjL[jh][0][h][jj * 2]) = s0;
        *reinterpret_cast<float2*>(&Ej5L[jh][0][h][jj * 2]) = s1;
    }
    __syncthreads();

    int cur = 0;
    for (int c = 0; c < 8; ++c) {
        // ---- issue next chunk's loads (c=7 over-reads land in adjacent ws
        //      buffers: in-bounds, staged, never computed)
        const int jn = jbase + (c + 1) * 128;
        vN0 = *reinterpret_cast<const bf16x8*>(&vrow[jn + jaof]);
        vN1 = *reinterpret_cast<const bf16x8*>(&vrow[jn + 32 + jaof]);
        vN2 = *reinterpret_cast<const bf16x8*>(&vrow[jn + 64 + jaof]);
        vN3 = *reinterpret_cast<const bf16x8*>(&vrow[jn + 96 + jaof]);
        const float2 sn  = *reinterpret_cast<const float2*>(&EjG[jn + jj * 2]);
        const float2 sn5 = *reinterpret_cast<const float2*>(&Ej5G[jn + jj * 2]);
        __builtin_amdgcn_sched_barrier(0);

        // ---- masks for current chunk (block-uniform -> scalar loads)
        const u64* tmw = tmrow + (jh * 16 + c * 2) * 16;
        u64 mwA[16], mwB[16];
        #pragma unroll
        for (int e2 = 0; e2 < 16; ++e2) mwA[e2] = tmw[e2];
        #pragma unroll
        for (int e2 = 0; e2 < 16; ++e2) mwB[e2] = tmw[16 + e2];

        // ---- compute current chunk: 4 kk x (Ej from LDS, V from regs)
        #pragma unroll
        for (int kk = 0; kk < 4; ++kk) {
            const int jloc = kk * 32 + jaof;
            const float4 e0 = *reinterpret_cast<const float4*>(&EjL[jh][cur][h][jloc]);
            const float4 e1 = *reinterpret_cast<const float4*>(&EjL[jh][cur][h][jloc + 4]);
            const float4 f0 = *reinterpret_cast<const float4*>(&Ej5L[jh][cur][h][jloc]);
            const float4 f1 = *reinterpret_cast<const float4*>(&Ej5L[jh][cur][h][jloc + 4]);
            const bf16x8 v = (kk == 0) ? vC0 : (kk == 1) ? vC1 : (kk == 2) ? vC2 : vC3;
            const u64* mwp = (kk < 2) ? mwA : mwB;
            const int mof = (kk & 1) * 8;
            bf16x8 afr;
            #pragma unroll
            for (int ep = 0; ep < 4; ++ep) {
                const float4 ejv = (ep & 2) ? e1 : e0;
                const float4 ej5 = (ep & 2) ? f1 : f0;
                f32x2 ejp, ej5p;
                if (ep & 1) { ejp[0]=ejv.z; ejp[1]=ejv.w; ej5p[0]=ej5.z; ej5p[1]=ej5.w; }
                else        { ejp[0]=ejv.x; ejp[1]=ejv.y; ej5p[0]=ej5.x; ej5p[1]=ej5.y; }
                const f32x2 t1 = EiE * ejp;
                const f32x2 t2 = Ei5E * ej5p;
#if __has_builtin(__builtin_elementwise_max)
                const f32x2 tm2 = __builtin_elementwise_max(t1, t2);
#else
                f32x2 tm2; tm2[0] = fmaxf(t1[0], t2[0]); tm2[1] = fmaxf(t1[1], t2[1]);
#endif
                afr[2 * ep]     = (__bf16)lsel(tm2[0], mwp[mof + 2 * ep],     lanebit);
                afr[2 * ep + 1] = (__bf16)lsel(tm2[1], mwp[mof + 2 * ep + 1], lanebit);
            }
            acc  = __builtin_amdgcn_mfma_f32_16x16x32_bf16(afr, v,    acc,  0, 0, 0);
            accS = __builtin_amdgcn_mfma_f32_16x16x32_bf16(afr, ones, accS, 0, 0, 0);
        }

        // ---- stage next Ej into other buffer; barrier drains vmcnt (V loads
        //      complete here = full-phase cover); rotate regs
        const int nb = cur ^ 1;
        *reinterpret_cast<float2*>(&EjL[jh][nb][h][jj * 2]) = sn;
        *reinterpret_cast<float2*>(&Ej5L[jh][nb][h][jj * 2]) = sn5;
        __syncthreads();
        vC0 = vN0; vC1 = vN1; vC2 = vN2; vC3 = vN3;
        cur = nb;
    }

    // ---- jh pair-combine (r8-proven). C/D: col = r, row = jg*4+q.
    if (jh == 1) {
        #pragma unroll
        for (int q = 0; q < 4; ++q)
            hacc[jg * 4 + q][h * 16 + r] = acc[q];
        if (r == 0) {
            #pragma unroll
            for (int q = 0; q < 4; ++q) hsum[h][jg * 4 + q] = accS[q];
        }
    }
    __syncthreads();
    if (jh == 0) {
        #pragma unroll
        for (int q = 0; q < 4; ++q) {
            const int row = jg * 4 + q;
            const float num = acc[q] + hacc[row][h * 16 + r];
            const float den = accS[q] + hsum[h][row];
            const float inv = (den > 0.f) ? 1.f / den : 0.f;  // empty row -> 0
            hacc[row][h * 16 + r] = num * inv;
        }
    }
    __syncthreads();

    // ---- fused out-proj + ELU: 1024 threads, 2 rows each
    const int f = tid & 127;
    const int rg = tid >> 7;  // 8 groups x 2 rows
    float o0 = 0.f, o1 = 0.f;
    for (int k = 0; k < 128; k += 4) {
        const float w0 = WoT[(k + 0) * 128 + f];
        const float w1 = WoT[(k + 1) * 128 + f];
        const float w2 = WoT[(k + 2) * 128 + f];
        const float w3 = WoT[(k + 3) * 128 + f];
        const float4 h0 = *reinterpret_cast<const float4*>(&hacc[rg * 2 + 0][k]);
        const float4 h1 = *reinterpret_cast<const float4*>(&hacc[rg * 2 + 1][k]);
        o0 += h0.x * w0 + h0.y * w1 + h0.z * w2 + h0.w * w3;
        o1 += h1.x * w0 + h1.y * w1 + h1.z * w2 + h1.w * w3;
    }
    const float bv = bo[f];
    float vv[2] = {o0 + bv, o1 + bv};
    #pragma unroll
    for (int q = 0; q < 2; ++q) {
        float v = vv[q];
        v = (v > 0.f) ? v : (__expf(v) - 1.f);
        out[(size_t)(b * 2048 + ibase + rg * 2 + q) * 128 + f] = v;
    }
}

extern "C" void kernel_launch(void* const* d_in, const int* in_sizes, int n_in,
                              void* d_out, int out_size, void* d_ws, size_t ws_size,
                              hipStream_t stream) {
    const float* x   = (const float*)d_in[0];
    const int*   adj = (const int*)d_in[1];
    const float* W   = (const float*)d_in[2];
    const float* a   = (const float*)d_in[3];
    const float* Wo  = (const float*)d_in[4];
    const float* bo  = (const float*)d_in[5];
    float* out = (float*)d_out;

    // ws: wxT 2MB | EI 512K | EjT 256K | Ej5T 256K | WoT 64K | tmask 2MB
    // (prefetch over-reads land in the NEXT buffer: in-bounds, discarded)
    char* ws = (char*)d_ws;
    unsigned short* wxT = (unsigned short*)ws;
    float2* EI  = (float2*)(ws + (size_t)2 * 1024 * 1024);
    float* EjT  = (float*)(EI + 4 * 8 * 2048);
    float* Ej5T = EjT + 4 * 8 * 2048;
    float* WoT  = Ej5T + 4 * 8 * 2048;
    u64* tmask = (u64*)(WoT + 128 * 128);

    prep_kernel<<<dim3(2048 + 1025), dim3(256), 0, stream>>>(
        x, W, a, Wo, adj, wxT, EI, EjT, Ej5T, WoT, tmask);
    gat_kernel<<<dim3(512), dim3(1024), 0, stream>>>(
        tmask, wxT, EI, EjT, Ej5T, WoT, bo, out);
}

// Round 14
// 108.681 us; speedup vs baseline: 1.7553x; 1.7553x over previous
//
#include <hip/hip_runtime.h>
#include <hip/hip_bf16.h>
#include <cstdint>

// GAT fused layer: B=4, N=2048, F=128, H=8, HD=16, all fp32 I/O.
// Identity: exp(leaky(si+sj)) = max(exp(si)exp(sj), exp(.2si)exp(.2sj))
// prep: blocks [0,2048) tpack (adj -> transposed u64 mask words), then proj,
//   then WoT (r11-proven).
// gat_part v14: 2048 blocks x 256 thr (4 waves = 4 heads), block =
//   (b, tile, jh half, head-group); __launch_bounds__(256,8) -> 8 blocks/CU
//   = 32 waves/CU WITHOUT register starvation (r13 lesson: 1024-thr blocks
//   at cap 64 spilled catastrophically). Barrier-free JIT j-loop: TLP at 8
//   waves/SIMD covers L2 latency. Masks: wave-uniform s_load +
//   inverse_ballot. Writes fp32 partials (pacc/psum) to ws.
// combine: 512 blocks x 256 thr: num/den pair-add, normalize, out-proj+ELU.

typedef float f32x2 __attribute__((ext_vector_type(2)));
typedef float f32x4 __attribute__((ext_vector_type(4)));
typedef __bf16 bf16x8 __attribute__((ext_vector_type(8)));
typedef unsigned long long u64;

__device__ __forceinline__ float lsel(float v, u64 m, u64 lanebit) {
#if __has_builtin(__builtin_amdgcn_inverse_ballot_w64)
    (void)lanebit;
    return __builtin_amdgcn_inverse_ballot_w64(m) ? v : 0.0f;
#else
    return (m & lanebit) ? v : 0.0f;
#endif
}

__global__ __launch_bounds__(256)
void prep_kernel(const float* __restrict__ x, const float* __restrict__ W,
                 const float* __restrict__ a, const float* __restrict__ Wo,
                 const int* __restrict__ adj,
                 unsigned short* __restrict__ wxT,
                 float2* __restrict__ EI,
                 float* __restrict__ EjT, float* __restrict__ Ej5T,
                 float* __restrict__ WoT,
                 u64* __restrict__ tmask)
{
    const int t = threadIdx.x;

    if (blockIdx.x < 2048) {
        // ---- tpack: adj -> transposed mask words (r11-proven)
        __shared__ int al[16][257];
        const int blk2 = blockIdx.x;
        const int b = blk2 >> 9;
        const int tile = (blk2 >> 2) & 127;
        const int jq = blk2 & 3;
        const int rowbase = b * 2048 + tile * 16;
        const int w = t >> 6, lane = t & 63;
        const int r = lane & 15, jg = lane >> 4;
        const int srow = t >> 4, scol = (t & 15) * 16;

        #pragma unroll
        for (int cc = 0; cc < 2; ++cc) {
            const int jc = jq * 512 + cc * 256;
            const int* gsrc = adj + (size_t)(rowbase + srow) * 2048 + jc + scol;
            #pragma unroll
            for (int q = 0; q < 4; ++q) {
                const int4 v = *reinterpret_cast<const int4*>(&gsrc[q * 4]);
                al[srow][scol + q * 4 + 0] = v.x;
                al[srow][scol + q * 4 + 1] = v.y;
                al[srow][scol + q * 4 + 2] = v.z;
                al[srow][scol + q * 4 + 3] = v.w;
            }
            __syncthreads();
            u64 myw = 0;
            #pragma unroll
            for (int kk = 0; kk < 2; ++kk) {
                const int c0 = w * 64 + kk * 32 + jg * 8;
                const int4 a0 = *reinterpret_cast<const int4*>(&al[r][c0]);
                const int4 a1 = *reinterpret_cast<const int4*>(&al[r][c0 + 4]);
                const int av[8] = {a0.x, a0.y, a0.z, a0.w, a1.x, a1.y, a1.z, a1.w};
                #pragma unroll
                for (int e = 0; e < 8; ++e) {
                    const u64 bal = __ballot(av[e] != 0);
                    const int widx = kk * 8 + e;
                    if (lane == widx) myw = bal;
                }
            }
            __syncthreads();
            const int jtw = jq * 8 + cc * 4 + w;
            if (lane < 16)
                tmask[((size_t)(b * 128 + tile) * 32 + jtw) * 16 + lane] = myw;
        }
        return;
    }

    // ---- proj: blocks [2048,3072), WoT block 3072 (t<128 active)
    const int blk = blockIdx.x - 2048;
    if (blk == 1024) {
        if (t < 128)
            for (int k = 0; k < 128; ++k)
                WoT[k * 128 + t] = Wo[t * 128 + k];
        return;
    }
    __shared__ float xl[8 * 128];
    __shared__ float xw[8 * 128];
    const int row0 = blk * 8;
    if (t < 128) {
        #pragma unroll
        for (int r = 0; r < 8; ++r)
            xl[r * 128 + t] = x[(size_t)(row0 + r) * 128 + t];
    }
    __syncthreads();

    if (t < 128) {
        float acc[8] = {0.f, 0.f, 0.f, 0.f, 0.f, 0.f, 0.f, 0.f};
        for (int k = 0; k < 128; k += 4) {
            const float w0 = W[(k + 0) * 128 + t];
            const float w1 = W[(k + 1) * 128 + t];
            const float w2 = W[(k + 2) * 128 + t];
            const float w3 = W[(k + 3) * 128 + t];
            #pragma unroll
            for (int r = 0; r < 8; ++r) {
                const float4 xv = *reinterpret_cast<const float4*>(&xl[r * 128 + k]);
                acc[r] += xv.x * w0 + xv.y * w1 + xv.z * w2 + xv.w * w3;
            }
        }
        #pragma unroll
        for (int r = 0; r < 8; ++r) xw[r * 128 + t] = acc[r];
    }
    __syncthreads();

    if (t < 128) {
        const int b = row0 >> 11, n0 = row0 & 2047;
        bf16x8 st;
        #pragma unroll
        for (int r = 0; r < 8; ++r) st[r] = (__bf16)xw[r * 128 + t];
        *reinterpret_cast<bf16x8*>(&wxT[((size_t)(b * 128 + t)) * 2048 + n0]) = st;

        const int r = t >> 4, h = (t >> 1) & 7, s = t & 1;
        float dot = 0.f;
        #pragma unroll
        for (int d = 0; d < 16; ++d)
            dot += xw[r * 128 + h * 16 + d] * a[h * 32 + s * 16 + d];
        const float ef  = __expf(dot);
        const float ef5 = __expf(0.2f * dot);
        const int idx = (b * 8 + h) * 2048 + n0 + r;
        if (s) { EjT[idx] = ef; Ej5T[idx] = ef5; }
        else   { float2 ev; ev.x = ef; ev.y = ef5; EI[idx] = ev; }
    }
}

__global__ __launch_bounds__(256, 8)
void gat_part(const u64* __restrict__ tmask,
              const unsigned short* __restrict__ wxT,
              const float2* __restrict__ EI,
              const float* __restrict__ EjT, const float* __restrict__ Ej5T,
              float* __restrict__ pacc, float* __restrict__ psum)
{
    const int tid = threadIdx.x;
    const int hw = tid >> 6;             // local head 0..3
    const int lane = tid & 63;
    const int r = lane & 15;             // A-frag row / B-frag col (feature)
    const int jg = lane >> 4;
    const int jaof = jg * 8;
    const u64 lanebit = 1ull << lane;
    // work mapping: all 4 blocks of one (b,tile) on one XCD (bijective)
    const int x = blockIdx.x & 7, w = blockIdx.x >> 3;   // w in 0..255
    const int tg = x * 64 + (w & 63);    // 0..511 = b*128+tile
    const int sub = w >> 6;              // 0..3
    const int jh = sub >> 1, hg = sub & 1;
    const int b = tg >> 7;
    const int tile = tg & 127;
    const int ibase = tile << 4;
    const int h = hg * 4 + hw;           // global head

    const int eb = (b * 8 + h) * 2048;
    const float2 q0 = EI[eb + ibase + r];
    f32x2 EiE, Ei5E;
    EiE[0] = q0.x; EiE[1] = q0.x; Ei5E[0] = q0.y; Ei5E[1] = q0.y;
    const float* EjR  = EjT  + eb;
    const float* Ej5R = Ej5T + eb;
    const unsigned short* vrow = wxT + ((size_t)(b * 128 + h * 16 + r)) * 2048;
    const u64* tmrow = tmask + (size_t)(b * 128 + tile) * 512 + jh * 256;

    f32x4 acc  = {0.f, 0.f, 0.f, 0.f};
    f32x4 accS = {0.f, 0.f, 0.f, 0.f};
    bf16x8 ones;
    #pragma unroll
    for (int e2 = 0; e2 < 8; ++e2) ones[e2] = (__bf16)1.0f;

    const int jbase = jh * 1024;
    for (int c = 0; c < 16; ++c) {
        const int j0 = jbase + c * 64;
        // masks (wave-uniform -> s_load)
        const u64* tmw = tmrow + c * 16;
        u64 mw[16];
        #pragma unroll
        for (int e2 = 0; e2 < 16; ++e2) mw[e2] = tmw[e2];

        #pragma unroll
        for (int kk = 0; kk < 2; ++kk) {
            const int ja = j0 + kk * 32 + jaof;
            const float4 e0 = *reinterpret_cast<const float4*>(&EjR[ja]);
            const float4 e1 = *reinterpret_cast<const float4*>(&EjR[ja + 4]);
            const float4 f0 = *reinterpret_cast<const float4*>(&Ej5R[ja]);
            const float4 f1 = *reinterpret_cast<const float4*>(&Ej5R[ja + 4]);
            const bf16x8 v = *reinterpret_cast<const bf16x8*>(&vrow[ja]);
            const int mof = kk * 8;
            bf16x8 afr;
            #pragma unroll
            for (int ep = 0; ep < 4; ++ep) {
                const float4 ejv = (ep & 2) ? e1 : e0;
                const float4 ej5 = (ep & 2) ? f1 : f0;
                f32x2 ejp, ej5p;
                if (ep & 1) { ejp[0]=ejv.z; ejp[1]=ejv.w; ej5p[0]=ej5.z; ej5p[1]=ej5.w; }
                else        { ejp[0]=ejv.x; ejp[1]=ejv.y; ej5p[0]=ej5.x; ej5p[1]=ej5.y; }
                const f32x2 t1 = EiE * ejp;
                const f32x2 t2 = Ei5E * ej5p;
#if __has_builtin(__builtin_elementwise_max)
                const f32x2 tm2 = __builtin_elementwise_max(t1, t2);
#else
                f32x2 tm2; tm2[0] = fmaxf(t1[0], t2[0]); tm2[1] = fmaxf(t1[1], t2[1]);
#endif
                afr[2 * ep]     = (__bf16)lsel(tm2[0], mw[mof + 2 * ep],     lanebit);
                afr[2 * ep + 1] = (__bf16)lsel(tm2[1], mw[mof + 2 * ep + 1], lanebit);
            }
            acc  = __builtin_amdgcn_mfma_f32_16x16x32_bf16(afr, v,    acc,  0, 0, 0);
            accS = __builtin_amdgcn_mfma_f32_16x16x32_bf16(afr, ones, accS, 0, 0, 0);
        }
    }

    // partials. C/D: col = r (feature), row = jg*4+q.
    const size_t pb = (size_t)((b * 128 + tile) * 2 + jh);
    float* pa = pacc + pb * 2048;
    float* ps = psum + pb * 128;
    #pragma unroll
    for (int q = 0; q < 4; ++q) {
        const int row = jg * 4 + q;
        pa[row * 128 + hg * 64 + hw * 16 + r] = acc[q];
        if (r == 0) ps[(hg * 4 + hw) * 16 + row] = accS[q];
    }
}

__global__ __launch_bounds__(256)
void combine_kernel(const float* __restrict__ pacc, const float* __restrict__ psum,
                    const float* __restrict__ WoT, const float* __restrict__ bo,
                    float* __restrict__ out)
{
    const int tid = threadIdx.x;
    const int bid = (blockIdx.x & 7) * 64 + (blockIdx.x >> 3);
    const int b = bid >> 7;
    const int tile = bid & 127;
    const int ibase = tile << 4;

    __shared__ float hl[16][128];
    const size_t pb0 = (size_t)((b * 128 + tile) * 2);
    const float* pa0 = pacc + pb0 * 2048;
    const float* pa1 = pa0 + 2048;
    const float* ps0 = psum + pb0 * 128;
    const float* ps1 = ps0 + 128;

    #pragma unroll
    for (int k = 0; k < 8; ++k) {
        const int idx = k * 256 + tid;        // 0..2047
        const int row = idx >> 7, f = idx & 127, h = f >> 4;
        const float num = pa0[idx] + pa1[idx];
        const float den = ps0[h * 16 + row] + ps1[h * 16 + row];
        const float inv = (den > 0.f) ? 1.f / den : 0.f;   // empty row -> 0
        hl[row][f] = num * inv;
    }
    __syncthreads();

    // out-proj + ELU: 256 thr = 2 groups x 8 rows
    const int f = tid & 127;
    const int rg = tid >> 7;
    float o[8] = {0.f, 0.f, 0.f, 0.f, 0.f, 0.f, 0.f, 0.f};
    for (int k = 0; k < 128; k += 4) {
        const float w0 = WoT[(k + 0) * 128 + f];
        const float w1 = WoT[(k + 1) * 128 + f];
        const float w2 = WoT[(k + 2) * 128 + f];
        const float w3 = WoT[(k + 3) * 128 + f];
        #pragma unroll
        for (int q = 0; q < 8; ++q) {
            const float4 hv = *reinterpret_cast<const float4*>(&hl[rg * 8 + q][k]);
            o[q] += hv.x * w0 + hv.y * w1 + hv.z * w2 + hv.w * w3;
        }
    }
    const float bv = bo[f];
    #pragma unroll
    for (int q = 0; q < 8; ++q) {
        float v = o[q] + bv;
        v = (v > 0.f) ? v : (__expf(v) - 1.f);
        out[(size_t)(b * 2048 + ibase + rg * 8 + q) * 128 + f] = v;
    }
}

extern "C" void kernel_launch(void* const* d_in, const int* in_sizes, int n_in,
                              void* d_out, int out_size, void* d_ws, size_t ws_size,
                              hipStream_t stream) {
    const float* x   = (const float*)d_in[0];
    const int*   adj = (const int*)d_in[1];
    const float* W   = (const float*)d_in[2];
    const float* a   = (const float*)d_in[3];
    const float* Wo  = (const float*)d_in[4];
    const float* bo  = (const float*)d_in[5];
    float* out = (float*)d_out;

    // ws: wxT 2MB | EI 512K | EjT 256K | Ej5T 256K | WoT 64K | tmask 2MB |
    //     pacc 8MB | psum 512K   (~13.6 MB total)
    char* ws = (char*)d_ws;
    unsigned short* wxT = (unsigned short*)ws;
    float2* EI  = (float2*)(ws + (size_t)2 * 1024 * 1024);
    float* EjT  = (float*)(EI + 4 * 8 * 2048);
    float* Ej5T = EjT + 4 * 8 * 2048;
    float* WoT  = Ej5T + 4 * 8 * 2048;
    u64* tmask = (u64*)(WoT + 128 * 128);
    float* pacc = (float*)(tmask + (size_t)512 * 512);
    float* psum = pacc + (size_t)1024 * 2048;

    prep_kernel<<<dim3(2048 + 1025), dim3(256), 0, stream>>>(
        x, W, a, Wo, adj, wxT, EI, EjT, Ej5T, WoT, tmask);
    gat_part<<<dim3(2048), dim3(256), 0, stream>>>(
        tmask, wxT, EI, EjT, Ej5T, pacc, psum);
    combine_kernel<<<dim3(512), dim3(256), 0, stream>>>(
        pacc, psum, WoT, bo, out);
}

// Round 15
// 72.283 us; speedup vs baseline: 2.6392x; 1.5035x over previous
//
#include <hip/hip_runtime.h>
#include <hip/hip_bf16.h>
#include <cstdint>

// GAT fused layer: B=4, N=2048, F=128, H=8, HD=16, all fp32 I/O.
// Identity: exp(leaky(si+sj)) = max(exp(si)exp(sj), exp(.2si)exp(.2sj))
// prep: blocks [0,2048) tpack (adj -> transposed u64 mask words), then proj,
//   then WoT (r11-proven).
// vshuf (NEW): wxT -> vfrag in MFMA-fragment order: vfrag[((b*8+h)*64+w32)*64
//   + lane] = 16B bf16x8 at feature h*16+(lane&15), j = w32*32+(lane>>4)*8.
//   Pays the 16-way-scattered read ONCE (2MB) instead of 128x per tile-block.
//   gat's V loads become fully-coalesced 1KB bursts (r1-r14 were L2-segment-
//   rate bound on scattered V: ~4e6 16B segments ~= the 45-50us gat plateau).
// gat: r12 structure unchanged except V reads vfrag coalesced.

typedef float f32x2 __attribute__((ext_vector_type(2)));
typedef float f32x4 __attribute__((ext_vector_type(4)));
typedef __bf16 bf16x8 __attribute__((ext_vector_type(8)));
typedef unsigned long long u64;

__device__ __forceinline__ float lsel(float v, u64 m, u64 lanebit) {
#if __has_builtin(__builtin_amdgcn_inverse_ballot_w64)
    (void)lanebit;
    return __builtin_amdgcn_inverse_ballot_w64(m) ? v : 0.0f;
#else
    return (m & lanebit) ? v : 0.0f;
#endif
}

__global__ __launch_bounds__(256)
void prep_kernel(const float* __restrict__ x, const float* __restrict__ W,
                 const float* __restrict__ a, const float* __restrict__ Wo,
                 const int* __restrict__ adj,
                 unsigned short* __restrict__ wxT,
                 float2* __restrict__ EI,
                 float* __restrict__ EjT, float* __restrict__ Ej5T,
                 float* __restrict__ WoT,
                 u64* __restrict__ tmask)
{
    const int t = threadIdx.x;

    if (blockIdx.x < 2048) {
        // ---- tpack: adj -> transposed mask words (r11-proven)
        __shared__ int al[16][257];
        const int blk2 = blockIdx.x;
        const int b = blk2 >> 9;
        const int tile = (blk2 >> 2) & 127;
        const int jq = blk2 & 3;
        const int rowbase = b * 2048 + tile * 16;
        const int w = t >> 6, lane = t & 63;
        const int r = lane & 15, jg = lane >> 4;
        const int srow = t >> 4, scol = (t & 15) * 16;

        #pragma unroll
        for (int cc = 0; cc < 2; ++cc) {
            const int jc = jq * 512 + cc * 256;
            const int* gsrc = adj + (size_t)(rowbase + srow) * 2048 + jc + scol;
            #pragma unroll
            for (int q = 0; q < 4; ++q) {
                const int4 v = *reinterpret_cast<const int4*>(&gsrc[q * 4]);
                al[srow][scol + q * 4 + 0] = v.x;
                al[srow][scol + q * 4 + 1] = v.y;
                al[srow][scol + q * 4 + 2] = v.z;
                al[srow][scol + q * 4 + 3] = v.w;
            }
            __syncthreads();
            u64 myw = 0;
            #pragma unroll
            for (int kk = 0; kk < 2; ++kk) {
                const int c0 = w * 64 + kk * 32 + jg * 8;
                const int4 a0 = *reinterpret_cast<const int4*>(&al[r][c0]);
                const int4 a1 = *reinterpret_cast<const int4*>(&al[r][c0 + 4]);
                const int av[8] = {a0.x, a0.y, a0.z, a0.w, a1.x, a1.y, a1.z, a1.w};
                #pragma unroll
                for (int e = 0; e < 8; ++e) {
                    const u64 bal = __ballot(av[e] != 0);
                    const int widx = kk * 8 + e;
                    if (lane == widx) myw = bal;
                }
            }
            __syncthreads();
            const int jtw = jq * 8 + cc * 4 + w;
            if (lane < 16)
                tmask[((size_t)(b * 128 + tile) * 32 + jtw) * 16 + lane] = myw;
        }
        return;
    }

    // ---- proj: blocks [2048,3072), WoT block 3072 (t<128 active)
    const int blk = blockIdx.x - 2048;
    if (blk == 1024) {
        if (t < 128)
            for (int k = 0; k < 128; ++k)
                WoT[k * 128 + t] = Wo[t * 128 + k];
        return;
    }
    __shared__ float xl[8 * 128];
    __shared__ float xw[8 * 128];
    const int row0 = blk * 8;
    if (t < 128) {
        #pragma unroll
        for (int r = 0; r < 8; ++r)
            xl[r * 128 + t] = x[(size_t)(row0 + r) * 128 + t];
    }
    __syncthreads();

    if (t < 128) {
        float acc[8] = {0.f, 0.f, 0.f, 0.f, 0.f, 0.f, 0.f, 0.f};
        for (int k = 0; k < 128; k += 4) {
            const float w0 = W[(k + 0) * 128 + t];
            const float w1 = W[(k + 1) * 128 + t];
            const float w2 = W[(k + 2) * 128 + t];
            const float w3 = W[(k + 3) * 128 + t];
            #pragma unroll
            for (int r = 0; r < 8; ++r) {
                const float4 xv = *reinterpret_cast<const float4*>(&xl[r * 128 + k]);
                acc[r] += xv.x * w0 + xv.y * w1 + xv.z * w2 + xv.w * w3;
            }
        }
        #pragma unroll
        for (int r = 0; r < 8; ++r) xw[r * 128 + t] = acc[r];
    }
    __syncthreads();

    if (t < 128) {
        const int b = row0 >> 11, n0 = row0 & 2047;
        bf16x8 st;
        #pragma unroll
        for (int r = 0; r < 8; ++r) st[r] = (__bf16)xw[r * 128 + t];
        *reinterpret_cast<bf16x8*>(&wxT[((size_t)(b * 128 + t)) * 2048 + n0]) = st;

        const int r = t >> 4, h = (t >> 1) & 7, s = t & 1;
        float dot = 0.f;
        #pragma unroll
        for (int d = 0; d < 16; ++d)
            dot += xw[r * 128 + h * 16 + d] * a[h * 32 + s * 16 + d];
        const float ef  = __expf(dot);
        const float ef5 = __expf(0.2f * dot);
        const int idx = (b * 8 + h) * 2048 + n0 + r;
        if (s) { EjT[idx] = ef; Ej5T[idx] = ef5; }
        else   { float2 ev; ev.x = ef; ev.y = ef5; EI[idx] = ev; }
    }
}

// wxT [b*128+f][2048 n] -> vfrag [((b*8+h)*64 + w32)*64 + lane] : bf16x8 at
// feature f = h*16 + (lane&15), j = w32*32 + (lane>>4)*8. Scattered read,
// coalesced write; 2MB total.
__global__ __launch_bounds__(256)
void vshuf_kernel(const unsigned short* __restrict__ wxT,
                  unsigned short* __restrict__ vfrag)
{
    const int gid = blockIdx.x * 256 + threadIdx.x;   // 0..131071
    const int lane = gid & 63;
    const int w32 = (gid >> 6) & 63;
    const int bh = gid >> 12;                          // b*8 + h
    const int b = bh >> 3, h = bh & 7;
    const int f = h * 16 + (lane & 15);
    const int j = w32 * 32 + (lane >> 4) * 8;
    const bf16x8 v = *reinterpret_cast<const bf16x8*>(
        &wxT[((size_t)(b * 128 + f)) * 2048 + j]);
    *reinterpret_cast<bf16x8*>(&vfrag[(size_t)gid * 8]) = v;
}

__global__ __launch_bounds__(512, 4)
void gat_kernel(const u64* __restrict__ tmask,
                const unsigned short* __restrict__ vfrag,
                const float2* __restrict__ EI,
                const float* __restrict__ EjT, const float* __restrict__ Ej5T,
                const float* __restrict__ WoT, const float* __restrict__ bo,
                float* __restrict__ out)
{
    const int tid = threadIdx.x;
    const int h = tid >> 6;              // wave = head
    const int lane = tid & 63;
    const int r = lane & 15;             // A-frag row / B-frag col (feature)
    const int jg = lane >> 4;
    const int jaof = jg * 8;
    const u64 lanebit = 1ull << lane;
    // XCD-aware bijective swizzle (512 % 8 == 0)
    const int bid = (blockIdx.x & 7) * 64 + (blockIdx.x >> 3);
    const int b = bid >> 7;
    const int tile = bid & 127;
    const int ibase = tile << 4;

    __shared__ __align__(16) float EjL[2][8][128];
    __shared__ __align__(16) float Ej5L[2][8][128];
    __shared__ float hacc[16][128];

    const int eb = (b * 8 + h) * 2048;
    const float2 q0 = EI[eb + ibase + r];
    f32x2 EiE, Ei5E;
    EiE[0] = q0.x; EiE[1] = q0.x; Ei5E[0] = q0.y; Ei5E[1] = q0.y;
    const u64* tmrow = tmask + (size_t)(b * 128 + tile) * 512;

    // V: coalesced MFMA-fragment loads (lane-contiguous 16B)
    const unsigned short* vfr = vfrag + (size_t)(b * 8 + h) * 64 * 64 * 8;
    const int jj = lane;
    const float* EjG  = EjT  + eb;
    const float* Ej5G = Ej5T + eb;

    f32x4 acc  = {0.f, 0.f, 0.f, 0.f};
    f32x4 accS = {0.f, 0.f, 0.f, 0.f};
    bf16x8 ones;
    #pragma unroll
    for (int e2 = 0; e2 < 8; ++e2) ones[e2] = (__bf16)1.0f;

    bf16x8 vC0, vC1, vC2, vC3, vN0, vN1, vN2, vN3;
    // ---- prologue: V chunk 0 (w32 = 0..3) -> regs, Ej chunk 0 -> LDS buf 0
    vC0 = *reinterpret_cast<const bf16x8*>(&vfr[(0 * 64 + lane) * 8]);
    vC1 = *reinterpret_cast<const bf16x8*>(&vfr[(1 * 64 + lane) * 8]);
    vC2 = *reinterpret_cast<const bf16x8*>(&vfr[(2 * 64 + lane) * 8]);
    vC3 = *reinterpret_cast<const bf16x8*>(&vfr[(3 * 64 + lane) * 8]);
    {
        const float2 s0 = *reinterpret_cast<const float2*>(&EjG[jj * 2]);
        const float2 s1 = *reinterpret_cast<const float2*>(&Ej5G[jj * 2]);
        *reinterpret_cast<float2*>(&EjL[0][h][jj * 2]) = s0;
        *reinterpret_cast<float2*>(&Ej5L[0][h][jj * 2]) = s1;
    }
    __syncthreads();

    int cur = 0;
    for (int c = 0; c < 16; ++c) {
        // ---- issue next chunk's loads (c=15 wraps: in-bounds, discarded)
        const int cn = (c + 1) & 15;
        const int w32n = cn * 4;
        const int jn = (c + 1) * 128;    // Ej over-read lands in next ws buf
        vN0 = *reinterpret_cast<const bf16x8*>(&vfr[((w32n + 0) * 64 + lane) * 8]);
        vN1 = *reinterpret_cast<const bf16x8*>(&vfr[((w32n + 1) * 64 + lane) * 8]);
        vN2 = *reinterpret_cast<const bf16x8*>(&vfr[((w32n + 2) * 64 + lane) * 8]);
        vN3 = *reinterpret_cast<const bf16x8*>(&vfr[((w32n + 3) * 64 + lane) * 8]);
        const float2 sn  = *reinterpret_cast<const float2*>(&EjG[jn + jj * 2]);
        const float2 sn5 = *reinterpret_cast<const float2*>(&Ej5G[jn + jj * 2]);
        __builtin_amdgcn_sched_barrier(0);

        // ---- masks for current chunk (block-uniform -> scalar loads)
        const u64* tmw = tmrow + c * 32;
        u64 mwA[16], mwB[16];
        #pragma unroll
        for (int e2 = 0; e2 < 16; ++e2) mwA[e2] = tmw[e2];
        #pragma unroll
        for (int e2 = 0; e2 < 16; ++e2) mwB[e2] = tmw[16 + e2];

        // ---- compute current chunk: 4 kk x (Ej from LDS, V from regs)
        #pragma unroll
        for (int kk = 0; kk < 4; ++kk) {
            const int jloc = kk * 32 + jaof;
            const float4 e0 = *reinterpret_cast<const float4*>(&EjL[cur][h][jloc]);
            const float4 e1 = *reinterpret_cast<const float4*>(&EjL[cur][h][jloc + 4]);
            const float4 f0 = *reinterpret_cast<const float4*>(&Ej5L[cur][h][jloc]);
            const float4 f1 = *reinterpret_cast<const float4*>(&Ej5L[cur][h][jloc + 4]);
            const bf16x8 v = (kk == 0) ? vC0 : (kk == 1) ? vC1 : (kk == 2) ? vC2 : vC3;
            const u64* mwp = (kk < 2) ? mwA : mwB;
            const int mof = (kk & 1) * 8;
            bf16x8 afr;
            #pragma unroll
            for (int ep = 0; ep < 4; ++ep) {
                const float4 ejv = (ep & 2) ? e1 : e0;
                const float4 ej5 = (ep & 2) ? f1 : f0;
                f32x2 ejp, ej5p;
                if (ep & 1) { ejp[0]=ejv.z; ejp[1]=ejv.w; ej5p[0]=ej5.z; ej5p[1]=ej5.w; }
                else        { ejp[0]=ejv.x; ejp[1]=ejv.y; ej5p[0]=ej5.x; ej5p[1]=ej5.y; }
                const f32x2 t1 = EiE * ejp;
                const f32x2 t2 = Ei5E * ej5p;
#if __has_builtin(__builtin_elementwise_max)
                const f32x2 tm2 = __builtin_elementwise_max(t1, t2);
#else
                f32x2 tm2; tm2[0] = fmaxf(t1[0], t2[0]); tm2[1] = fmaxf(t1[1], t2[1]);
#endif
                afr[2 * ep]     = (__bf16)lsel(tm2[0], mwp[mof + 2 * ep],     lanebit);
                afr[2 * ep + 1] = (__bf16)lsel(tm2[1], mwp[mof + 2 * ep + 1], lanebit);
            }
            acc  = __builtin_amdgcn_mfma_f32_16x16x32_bf16(afr, v,    acc,  0, 0, 0);
            accS = __builtin_amdgcn_mfma_f32_16x16x32_bf16(afr, ones, accS, 0, 0, 0);
        }

        // ---- stage next Ej into other buffer; barrier drains vmcnt
        const int nb = cur ^ 1;
        *reinterpret_cast<float2*>(&EjL[nb][h][jj * 2]) = sn;
        *reinterpret_cast<float2*>(&Ej5L[nb][h][jj * 2]) = sn5;
        __syncthreads();
        vC0 = vN0; vC1 = vN1; vC2 = vN2; vC3 = vN3;
        cur = nb;
    }

    // C/D layout: col = lane&15 (=feature r), row = jg*4+q. accS[q] = row sum.
    #pragma unroll
    for (int q = 0; q < 4; ++q) {
        const int row = jg * 4 + q;
        const float inv = (accS[q] > 0.f) ? 1.f / accS[q] : 0.f;  // empty row -> 0
        hacc[row][h * 16 + r] = acc[q] * inv;
    }
    __syncthreads();

    // ---- fused out-proj + ELU: 512 threads, 4 rows each
    const int f = tid & 127;
    const int rg = tid >> 7;
    float o0 = 0.f, o1 = 0.f, o2 = 0.f, o3 = 0.f;
    for (int k = 0; k < 128; k += 4) {
        const float w0 = WoT[(k + 0) * 128 + f];
        const float w1 = WoT[(k + 1) * 128 + f];
        const float w2 = WoT[(k + 2) * 128 + f];
        const float w3 = WoT[(k + 3) * 128 + f];
        const float4 h0 = *reinterpret_cast<const float4*>(&hacc[rg * 4 + 0][k]);
        const float4 h1 = *reinterpret_cast<const float4*>(&hacc[rg * 4 + 1][k]);
        const float4 h2v = *reinterpret_cast<const float4*>(&hacc[rg * 4 + 2][k]);
        const float4 h3 = *reinterpret_cast<const float4*>(&hacc[rg * 4 + 3][k]);
        o0 += h0.x * w0 + h0.y * w1 + h0.z * w2 + h0.w * w3;
        o1 += h1.x * w0 + h1.y * w1 + h1.z * w2 + h1.w * w3;
        o2 += h2v.x * w0 + h2v.y * w1 + h2v.z * w2 + h2v.w * w3;
        o3 += h3.x * w0 + h3.y * w1 + h3.z * w2 + h3.w * w3;
    }
    const float bv = bo[f];
    float vv[4] = {o0 + bv, o1 + bv, o2 + bv, o3 + bv};
    #pragma unroll
    for (int q = 0; q < 4; ++q) {
        float v = vv[q];
        v = (v > 0.f) ? v : (__expf(v) - 1.f);
        out[(size_t)(b * 2048 + ibase + rg * 4 + q) * 128 + f] = v;
    }
}

extern "C" void kernel_launch(void* const* d_in, const int* in_sizes, int n_in,
                              void* d_out, int out_size, void* d_ws, size_t ws_size,
                              hipStream_t stream) {
    const float* x   = (const float*)d_in[0];
    const int*   adj = (const int*)d_in[1];
    const float* W   = (const float*)d_in[2];
    const float* a   = (const float*)d_in[3];
    const float* Wo  = (const float*)d_in[4];
    const float* bo  = (const float*)d_in[5];
    float* out = (float*)d_out;

    // ws: wxT 2MB | EI 512K | EjT 256K | Ej5T 256K | WoT 64K | tmask 2MB | vfrag 2MB
    char* ws = (char*)d_ws;
    unsigned short* wxT = (unsigned short*)ws;
    float2* EI  = (float2*)(ws + (size_t)2 * 1024 * 1024);
    float* EjT  = (float*)(EI + 4 * 8 * 2048);
    float* Ej5T = EjT + 4 * 8 * 2048;
    float* WoT  = Ej5T + 4 * 8 * 2048;
    u64* tmask = (u64*)(WoT + 128 * 128);
    unsigned short* vfrag = (unsigned short*)(tmask + (size_t)512 * 512);

    prep_kernel<<<dim3(2048 + 1025), dim3(256), 0, stream>>>(
        x, W, a, Wo, adj, wxT, EI, EjT, Ej5T, WoT, tmask);
    vshuf_kernel<<<dim3(512), dim3(256), 0, stream>>>(wxT, vfrag);
    gat_kernel<<<dim3(512), dim3(512), 0, stream>>>(
        tmask, vfrag, EI, EjT, Ej5T, WoT, bo, out);
}